// Round 1
// baseline (885.906 us; speedup 1.0000x reference)
//
#include <hip/hip_runtime.h>
#include <hip/hip_bf16.h>

#define SEQ   512
#define BATCH 256
#define EMB   200
#define HID   50
#define G3    150     // 3*HID
#define MLPN  100

// ---------------------------------------------------------------------------
// k1: gx[t][b][0:150] = emb[tok] @ Wih_f.T + bih_f ; [150:300] same for _b
// 32 rows/block staged in LDS; thread j<150 computes col j for both dirs.
// ---------------------------------------------------------------------------
__global__ __launch_bounds__(192) void k1_gx(
    const int* __restrict__ tokens, const float* __restrict__ emb,
    const float* __restrict__ Wih_f, const float* __restrict__ bih_f,
    const float* __restrict__ Wih_b, const float* __restrict__ bih_b,
    float* __restrict__ gx)
{
    __shared__ float4 et[32 * 50];   // 32 rows x 200 floats
    __shared__ int tok[32];
    const int tid = threadIdx.x;
    const long row0 = (long)blockIdx.x * 32;

    if (tid < 32) tok[tid] = tokens[row0 + tid];
    __syncthreads();
    for (int idx = tid; idx < 32 * 50; idx += 192) {
        int r = idx / 50, k4 = idx % 50;
        et[idx] = reinterpret_cast<const float4*>(emb + (long)tok[r] * EMB)[k4];
    }
    __syncthreads();

    const int j = tid;
    if (j < G3) {
        float accf[32], accb[32];
        const float bf = bih_f[j], bb = bih_b[j];
        #pragma unroll
        for (int r = 0; r < 32; r++) { accf[r] = bf; accb[r] = bb; }
        const float4* wf = reinterpret_cast<const float4*>(Wih_f + j * EMB);
        const float4* wb = reinterpret_cast<const float4*>(Wih_b + j * EMB);
        for (int k4 = 0; k4 < 50; k4++) {
            float4 a = wf[k4], c = wb[k4];
            #pragma unroll
            for (int r = 0; r < 32; r++) {
                float4 e = et[r * 50 + k4];
                accf[r] += a.x * e.x + a.y * e.y + a.z * e.z + a.w * e.w;
                accb[r] += c.x * e.x + c.y * e.y + c.z * e.z + c.w * e.w;
            }
        }
        for (int r = 0; r < 32; r++) {
            long row = row0 + r;
            gx[row * 300 + j]       = accf[r];
            gx[row * 300 + 150 + j] = accb[r];
        }
    }
}

// ---------------------------------------------------------------------------
// k2: GRU scan. One block per (batch, direction); Whh row in registers,
// h broadcast via LDS. PyTorch gate order [r,z,n].
// ---------------------------------------------------------------------------
__global__ __launch_bounds__(192) void k2_gru(
    const float* __restrict__ gx,
    const float* __restrict__ Whh_f, const float* __restrict__ bhh_f,
    const float* __restrict__ Whh_b, const float* __restrict__ bhh_b,
    float* __restrict__ h)
{
    const int b   = blockIdx.x & 255;
    const int dir = blockIdx.x >> 8;
    const float* Whh = dir ? Whh_b : Whh_f;
    const float* bhh = dir ? bhh_b : bhh_f;
    const int j = threadIdx.x;

    __shared__ float hs[HID];
    __shared__ float ghs[G3];
    __shared__ float gxs[G3];

    float w[HID];
    float bj = 0.f;
    if (j < G3) {
        bj = bhh[j];
        #pragma unroll
        for (int k = 0; k < HID; k++) w[k] = Whh[j * HID + k];
    }
    if (j < HID) hs[j] = 0.f;
    float hold = 0.f;
    __syncthreads();

    for (int s = 0; s < SEQ; s++) {
        const int t = dir ? (SEQ - 1 - s) : s;
        float gxv = 0.f;
        float acc = bj;
        if (j < G3) {
            gxv = gx[((long)t * BATCH + b) * 300 + dir * 150 + j];
            #pragma unroll
            for (int k = 0; k < HID; k++) acc += w[k] * hs[k];
            ghs[j] = acc;
            gxs[j] = gxv;
        }
        __syncthreads();
        if (j < HID) {
            float ghr = ghs[j], ghz = ghs[j + HID], ghn = ghs[j + 2 * HID];
            float gxr = gxs[j], gxz = gxs[j + HID], gxn = gxs[j + 2 * HID];
            float r = 1.f / (1.f + __expf(-(gxr + ghr)));
            float z = 1.f / (1.f + __expf(-(gxz + ghz)));
            float x = gxn + r * ghn;
            float e2 = __expf(-2.f * x);
            float n = (1.f - e2) / (1.f + e2);
            float hn = (1.f - z) * n + z * hold;
            hold = hn;
            hs[j] = hn;
            h[((long)t * BATCH + b) * 100 + dir * HID + j] = hn;
        }
        __syncthreads();
    }
}

// ---------------------------------------------------------------------------
// k3: scores[t][b] = sum_j ctx[j] * tanh(W_mlp[j]·h[t][b] + b_mlp[j])
// Thread-per-row; W_mlp in LDS (broadcast reads), h row in registers.
// Writes transposed scT[b][t] for k4's coalesced column read.
// ---------------------------------------------------------------------------
__global__ __launch_bounds__(256) void k3_scores(
    const float* __restrict__ h, const float* __restrict__ W_mlp,
    const float* __restrict__ b_mlp, const float* __restrict__ ctx,
    float* __restrict__ scT)
{
    __shared__ float4 Wm[MLPN * 25];
    __shared__ float bm[MLPN], cx[MLPN];
    const int tid = threadIdx.x;
    for (int idx = tid; idx < MLPN * 25; idx += 256)
        Wm[idx] = reinterpret_cast<const float4*>(W_mlp)[idx];
    if (tid < MLPN) { bm[tid] = b_mlp[tid]; cx[tid] = ctx[tid]; }
    __syncthreads();

    const long row = (long)blockIdx.x * 256 + tid;
    float4 hr[25];
    const float4* hp = reinterpret_cast<const float4*>(h + row * 100);
    #pragma unroll
    for (int i = 0; i < 25; i++) hr[i] = hp[i];

    float s = 0.f;
    for (int jj = 0; jj < MLPN; jj++) {
        float acc = bm[jj];
        #pragma unroll
        for (int i = 0; i < 25; i++) {
            float4 wv = Wm[jj * 25 + i];
            acc += wv.x * hr[i].x + wv.y * hr[i].y + wv.z * hr[i].z + wv.w * hr[i].w;
        }
        float e2 = __expf(-2.f * acc);
        float u = (1.f - e2) / (1.f + e2);
        s += u * cx[jj];
    }
    const int t = (int)(row >> 8);
    const int b = (int)(row & 255);
    scT[(long)b * SEQ + t] = s;
}

// ---------------------------------------------------------------------------
// k4: per-batch softmax over t, then doc[b][i] = sum_t alpha[t]*h[t][b][i]
// ---------------------------------------------------------------------------
__global__ __launch_bounds__(128) void k4_doc(
    const float* __restrict__ h, const float* __restrict__ scT,
    float* __restrict__ out)
{
    const int b = blockIdx.x;
    const int tid = threadIdx.x;
    __shared__ float al[SEQ];
    __shared__ float red[128];

    float4 sv = reinterpret_cast<const float4*>(scT + (long)b * SEQ)[tid];
    float m = fmaxf(fmaxf(sv.x, sv.y), fmaxf(sv.z, sv.w));
    red[tid] = m;
    __syncthreads();
    if (tid < 64) red[tid] = fmaxf(red[tid], red[tid + 64]);
    __syncthreads();
    if (tid < 64) {
        float v = red[tid];
        for (int o = 32; o > 0; o >>= 1) v = fmaxf(v, __shfl_down(v, o));
        if (tid == 0) red[0] = v;
    }
    __syncthreads();
    m = red[0];
    float e0 = __expf(sv.x - m), e1 = __expf(sv.y - m);
    float e2 = __expf(sv.z - m), e3 = __expf(sv.w - m);
    float psum = e0 + e1 + e2 + e3;
    __syncthreads();
    red[tid] = psum;
    __syncthreads();
    if (tid < 64) red[tid] += red[tid + 64];
    __syncthreads();
    if (tid < 64) {
        float v = red[tid];
        for (int o = 32; o > 0; o >>= 1) v += __shfl_down(v, o);
        if (tid == 0) red[0] = v;
    }
    __syncthreads();
    const float inv = 1.f / red[0];
    al[tid * 4 + 0] = e0 * inv;
    al[tid * 4 + 1] = e1 * inv;
    al[tid * 4 + 2] = e2 * inv;
    al[tid * 4 + 3] = e3 * inv;
    __syncthreads();

    if (tid < MLPN) {
        float acc = 0.f;
        for (int t = 0; t < SEQ; t++)
            acc += al[t] * h[((long)t * BATCH + b) * 100 + tid];
        out[(long)b * 100 + tid] = acc;
    }
}

// ---------------------------------------------------------------------------
extern "C" void kernel_launch(void* const* d_in, const int* in_sizes, int n_in,
                              void* d_out, int out_size, void* d_ws, size_t ws_size,
                              hipStream_t stream)
{
    const int*   tokens = (const int*)d_in[0];
    const float* emb    = (const float*)d_in[1];
    const float* Wih_f  = (const float*)d_in[2];
    const float* Whh_f  = (const float*)d_in[3];
    const float* bih_f  = (const float*)d_in[4];
    const float* bhh_f  = (const float*)d_in[5];
    const float* Wih_b  = (const float*)d_in[6];
    const float* Whh_b  = (const float*)d_in[7];
    const float* bih_b  = (const float*)d_in[8];
    const float* bhh_b  = (const float*)d_in[9];
    const float* W_mlp  = (const float*)d_in[10];
    const float* b_mlp  = (const float*)d_in[11];
    const float* ctx    = (const float*)d_in[12];
    float* out = (float*)d_out;

    float* gx  = (float*)d_ws;                         // SEQ*BATCH*300
    float* h   = gx + (size_t)SEQ * BATCH * 300;       // SEQ*BATCH*100
    float* scT = h  + (size_t)SEQ * BATCH * 100;       // BATCH*SEQ

    k1_gx<<<4096, 192, 0, stream>>>(tokens, emb, Wih_f, bih_f, Wih_b, bih_b, gx);
    k2_gru<<<512, 192, 0, stream>>>(gx, Whh_f, bhh_f, Whh_b, bhh_b, h);
    k3_scores<<<512, 256, 0, stream>>>(h, W_mlp, b_mlp, ctx, scT);
    k4_doc<<<256, 128, 0, stream>>>(h, scT, out);
}

// Round 2
// 601.991 us; speedup vs baseline: 1.4716x; 1.4716x over previous
//
#include <hip/hip_runtime.h>
#include <hip/hip_bf16.h>

#define SEQ   512
#define BATCH 256
#define EMB   200
#define HID   50
#define G3    150     // 3*HID
#define MLPN  100

typedef __attribute__((ext_vector_type(8))) short bf16x8;
typedef __attribute__((ext_vector_type(4))) float f32x4;

__device__ __forceinline__ unsigned short f2bf(float x) {
    unsigned u = __float_as_uint(x);
    unsigned r = (u + 0x7FFFu + ((u >> 16) & 1u)) >> 16;   // RNE
    return (unsigned short)r;
}

#define GLOAD_LDS16(g, s) __builtin_amdgcn_global_load_lds( \
    (const __attribute__((address_space(1))) void*)(g),     \
    (__attribute__((address_space(3))) void*)(s), 16, 0, 0)

// ---------------------------------------------------------------------------
// k0: convert Wih_f/Wih_b fp32 -> bf16 into padded layout Wpad[320][224]
// rows 0..149 = Wih_f, 160..309 = Wih_b; zeros elsewhere (N,K padding).
// ---------------------------------------------------------------------------
__global__ __launch_bounds__(256) void k0_wpad(
    const float* __restrict__ Wih_f, const float* __restrict__ Wih_b,
    unsigned short* __restrict__ Wpad)
{
    int idx = blockIdx.x * 256 + threadIdx.x;
    if (idx >= 320 * 224) return;
    int row = idx / 224;
    int k   = idx - row * 224;
    int d   = row / 160;
    int r   = row - d * 160;
    float v = 0.f;
    if (r < G3 && k < EMB) v = (d ? Wih_b : Wih_f)[r * EMB + k];
    Wpad[idx] = f2bf(v);
}

// ---------------------------------------------------------------------------
// k1: gx = emb[tok] @ [Wih_f;Wih_b].T + bias, via bf16 MFMA 16x16x32.
// 2048 blocks x 256 thr; BM=64 (16 rows/wave), N=320 (20 tiles/wave), K=7x32.
// ---------------------------------------------------------------------------
__global__ __launch_bounds__(256) void k1_gx(
    const int* __restrict__ tokens, const float* __restrict__ emb,
    const unsigned short* __restrict__ Wpad,
    const float* __restrict__ bih_f, const float* __restrict__ bih_b,
    float* __restrict__ gx)
{
    __shared__ unsigned short Abuf[64 * 32];    // 4 KB
    __shared__ unsigned short Bbuf[320 * 32];   // 20 KB
    __shared__ float bias[320];
    __shared__ int tok[64];

    const int t = threadIdx.x;
    const int w = t >> 6;
    const int l = t & 63;
    const long row0 = (long)blockIdx.x * 64;

    for (int idx = t; idx < 320; idx += 256) {
        int d = idx / 160, r = idx - d * 160;
        bias[idx] = (r < G3) ? (d ? bih_b[r] : bih_f[r]) : 0.f;
    }
    if (t < 64) tok[t] = tokens[row0 + t];

    f32x4 acc[20];
    #pragma unroll
    for (int nt = 0; nt < 20; nt++) acc[nt] = (f32x4){0.f, 0.f, 0.f, 0.f};

    const int ar = t >> 2;     // A row this thread stages (0..63)
    const int kq = t & 3;      // which 8-k group
    __syncthreads();           // tok/bias ready

    for (int c = 0; c < 7; c++) {
        const int kc0 = c * 32;
        // issue A loads early (before barrier) to hide latency
        float4 v0 = {0,0,0,0}, v1 = {0,0,0,0};
        if (kc0 + kq * 8 < EMB) {
            const float* src = emb + (long)tok[ar] * EMB + kc0 + kq * 8;
            v0 = *reinterpret_cast<const float4*>(src);
            v1 = *reinterpret_cast<const float4*>(src + 4);
        }
        __syncthreads();       // previous iter's frag reads done
        // A: convert + pack to LDS (two b64 writes)
        unsigned p0 = f2bf(v0.x) | ((unsigned)f2bf(v0.y) << 16);
        unsigned p1 = f2bf(v0.z) | ((unsigned)f2bf(v0.w) << 16);
        unsigned p2 = f2bf(v1.x) | ((unsigned)f2bf(v1.y) << 16);
        unsigned p3 = f2bf(v1.z) | ((unsigned)f2bf(v1.w) << 16);
        *reinterpret_cast<uint2*>(&Abuf[ar * 32 + kq * 8])     = make_uint2(p0, p1);
        *reinterpret_cast<uint2*>(&Abuf[ar * 32 + kq * 8 + 4]) = make_uint2(p2, p3);
        // B: async global->LDS, 5 x 1KB per wave (wave w covers rows w*80..+79)
        #pragma unroll
        for (int q = 0; q < 5; q++) {
            const int rbase = w * 80 + q * 16;
            const int rb = rbase + (l >> 2);
            const unsigned short* gsrc = Wpad + (long)rb * 224 + kc0 + (l & 3) * 8;
            GLOAD_LDS16(gsrc, &Bbuf[rbase * 32]);
        }
        __syncthreads();       // drains vmcnt+lgkmcnt: A and B ready
        // compute: 1 A-frag + 20 B-frags, 20 MFMAs
        bf16x8 af = *reinterpret_cast<bf16x8*>(&Abuf[(w * 16 + (l & 15)) * 32 + (l >> 4) * 8]);
        #pragma unroll
        for (int nt = 0; nt < 20; nt++) {
            bf16x8 bfr = *reinterpret_cast<bf16x8*>(&Bbuf[(nt * 16 + (l & 15)) * 32 + (l >> 4) * 8]);
            acc[nt] = __builtin_amdgcn_mfma_f32_16x16x32_bf16(af, bfr, acc[nt], 0, 0, 0);
        }
    }

    // epilogue: D mapping col=lane&15, row=(lane>>4)*4+i  [m89]
    const int colL  = l & 15;
    const int rquad = l >> 4;
    #pragma unroll
    for (int nt = 0; nt < 20; nt++) {
        int pcol = nt * 16 + colL;
        int d = pcol / 160;
        int jc = pcol - d * 160;
        if (jc >= G3) continue;
        float bv = bias[pcol];
        long col = d * G3 + jc;
        #pragma unroll
        for (int i = 0; i < 4; i++) {
            long row = row0 + w * 16 + rquad * 4 + i;
            gx[row * 300 + col] = acc[nt][i] + bv;
        }
    }
}

// ---------------------------------------------------------------------------
// k2: GRU scan. One block per (batch, direction); Whh row in registers,
// h broadcast via LDS. PyTorch gate order [r,z,n].
// ---------------------------------------------------------------------------
__global__ __launch_bounds__(192) void k2_gru(
    const float* __restrict__ gx,
    const float* __restrict__ Whh_f, const float* __restrict__ bhh_f,
    const float* __restrict__ Whh_b, const float* __restrict__ bhh_b,
    float* __restrict__ h)
{
    const int b   = blockIdx.x & 255;
    const int dir = blockIdx.x >> 8;
    const float* Whh = dir ? Whh_b : Whh_f;
    const float* bhh = dir ? bhh_b : bhh_f;
    const int j = threadIdx.x;

    __shared__ float hs[HID];
    __shared__ float ghs[G3];
    __shared__ float gxs[G3];

    float w[HID];
    float bj = 0.f;
    if (j < G3) {
        bj = bhh[j];
        #pragma unroll
        for (int k = 0; k < HID; k++) w[k] = Whh[j * HID + k];
    }
    if (j < HID) hs[j] = 0.f;
    float hold = 0.f;
    __syncthreads();

    for (int s = 0; s < SEQ; s++) {
        const int t = dir ? (SEQ - 1 - s) : s;
        float acc = bj;
        if (j < G3) {
            float gxv = gx[((long)t * BATCH + b) * 300 + dir * G3 + j];
            #pragma unroll
            for (int k = 0; k < HID; k++) acc += w[k] * hs[k];
            ghs[j] = acc;
            gxs[j] = gxv;
        }
        __syncthreads();
        if (j < HID) {
            float ghr = ghs[j], ghz = ghs[j + HID], ghn = ghs[j + 2 * HID];
            float gxr = gxs[j], gxz = gxs[j + HID], gxn = gxs[j + 2 * HID];
            float r = 1.f / (1.f + __expf(-(gxr + ghr)));
            float z = 1.f / (1.f + __expf(-(gxz + ghz)));
            float x = gxn + r * ghn;
            float e2 = __expf(-2.f * x);
            float n = (1.f - e2) / (1.f + e2);
            float hn = (1.f - z) * n + z * hold;
            hold = hn;
            hs[j] = hn;
            h[((long)t * BATCH + b) * 100 + dir * HID + j] = hn;
        }
        __syncthreads();
    }
}

// ---------------------------------------------------------------------------
// k3: scores via thread-per-row; W_mlp in LDS, h row in registers.
// ---------------------------------------------------------------------------
__global__ __launch_bounds__(256) void k3_scores(
    const float* __restrict__ h, const float* __restrict__ W_mlp,
    const float* __restrict__ b_mlp, const float* __restrict__ ctx,
    float* __restrict__ scT)
{
    __shared__ float4 Wm[MLPN * 25];
    __shared__ float bm[MLPN], cx[MLPN];
    const int tid = threadIdx.x;
    for (int idx = tid; idx < MLPN * 25; idx += 256)
        Wm[idx] = reinterpret_cast<const float4*>(W_mlp)[idx];
    if (tid < MLPN) { bm[tid] = b_mlp[tid]; cx[tid] = ctx[tid]; }
    __syncthreads();

    const long row = (long)blockIdx.x * 256 + tid;
    float4 hr[25];
    const float4* hp = reinterpret_cast<const float4*>(h + row * 100);
    #pragma unroll
    for (int i = 0; i < 25; i++) hr[i] = hp[i];

    float s = 0.f;
    for (int jj = 0; jj < MLPN; jj++) {
        float acc = bm[jj];
        #pragma unroll
        for (int i = 0; i < 25; i++) {
            float4 wv = Wm[jj * 25 + i];
            acc += wv.x * hr[i].x + wv.y * hr[i].y + wv.z * hr[i].z + wv.w * hr[i].w;
        }
        float e2 = __expf(-2.f * acc);
        float u = (1.f - e2) / (1.f + e2);
        s += u * cx[jj];
    }
    const int t = (int)(row >> 8);
    const int b = (int)(row & 255);
    scT[(long)b * SEQ + t] = s;
}

// ---------------------------------------------------------------------------
// k4: per-batch softmax over t, then doc[b][i] = sum_t alpha[t]*h[t][b][i]
// ---------------------------------------------------------------------------
__global__ __launch_bounds__(128) void k4_doc(
    const float* __restrict__ h, const float* __restrict__ scT,
    float* __restrict__ out)
{
    const int b = blockIdx.x;
    const int tid = threadIdx.x;
    __shared__ float al[SEQ];
    __shared__ float red[128];

    float4 sv = reinterpret_cast<const float4*>(scT + (long)b * SEQ)[tid];
    float m = fmaxf(fmaxf(sv.x, sv.y), fmaxf(sv.z, sv.w));
    red[tid] = m;
    __syncthreads();
    if (tid < 64) red[tid] = fmaxf(red[tid], red[tid + 64]);
    __syncthreads();
    if (tid < 64) {
        float v = red[tid];
        for (int o = 32; o > 0; o >>= 1) v = fmaxf(v, __shfl_down(v, o));
        if (tid == 0) red[0] = v;
    }
    __syncthreads();
    m = red[0];
    float e0 = __expf(sv.x - m), e1 = __expf(sv.y - m);
    float e2 = __expf(sv.z - m), e3 = __expf(sv.w - m);
    float psum = e0 + e1 + e2 + e3;
    __syncthreads();
    red[tid] = psum;
    __syncthreads();
    if (tid < 64) red[tid] += red[tid + 64];
    __syncthreads();
    if (tid < 64) {
        float v = red[tid];
        for (int o = 32; o > 0; o >>= 1) v += __shfl_down(v, o);
        if (tid == 0) red[0] = v;
    }
    __syncthreads();
    const float inv = 1.f / red[0];
    al[tid * 4 + 0] = e0 * inv;
    al[tid * 4 + 1] = e1 * inv;
    al[tid * 4 + 2] = e2 * inv;
    al[tid * 4 + 3] = e3 * inv;
    __syncthreads();

    if (tid < MLPN) {
        float acc = 0.f;
        for (int t = 0; t < SEQ; t++)
            acc += al[t] * h[((long)t * BATCH + b) * 100 + tid];
        out[(long)b * 100 + tid] = acc;
    }
}

// ---------------------------------------------------------------------------
extern "C" void kernel_launch(void* const* d_in, const int* in_sizes, int n_in,
                              void* d_out, int out_size, void* d_ws, size_t ws_size,
                              hipStream_t stream)
{
    const int*   tokens = (const int*)d_in[0];
    const float* emb    = (const float*)d_in[1];
    const float* Wih_f  = (const float*)d_in[2];
    const float* Whh_f  = (const float*)d_in[3];
    const float* bih_f  = (const float*)d_in[4];
    const float* bhh_f  = (const float*)d_in[5];
    const float* Wih_b  = (const float*)d_in[6];
    const float* Whh_b  = (const float*)d_in[7];
    const float* bih_b  = (const float*)d_in[8];
    const float* bhh_b  = (const float*)d_in[9];
    const float* W_mlp  = (const float*)d_in[10];
    const float* b_mlp  = (const float*)d_in[11];
    const float* ctx    = (const float*)d_in[12];
    float* out = (float*)d_out;

    float* gx  = (float*)d_ws;                         // SEQ*BATCH*300
    float* h   = gx + (size_t)SEQ * BATCH * 300;       // SEQ*BATCH*100
    float* scT = h  + (size_t)SEQ * BATCH * 100;       // BATCH*SEQ
    // Wpad (bf16 320x224 = 140 KB) aliases scT's region (512 KB):
    // k0 writes it, k1 reads it, and it's dead before k3 writes scT.
    unsigned short* Wpad = (unsigned short*)scT;

    k0_wpad<<<280, 256, 0, stream>>>(Wih_f, Wih_b, Wpad);
    k1_gx<<<2048, 256, 0, stream>>>(tokens, emb, Wpad, bih_f, bih_b, gx);
    k2_gru<<<512, 192, 0, stream>>>(gx, Whh_f, bhh_f, Whh_b, bhh_b, h);
    k3_scores<<<512, 256, 0, stream>>>(h, W_mlp, b_mlp, ctx, scT);
    k4_doc<<<256, 128, 0, stream>>>(h, scT, out);
}

// Round 3
// 485.712 us; speedup vs baseline: 1.8239x; 1.2394x over previous
//
#include <hip/hip_runtime.h>
#include <hip/hip_bf16.h>

#define SEQ   512
#define BATCH 256
#define EMB   200
#define HID   50
#define G3    150     // 3*HID
#define MLPN  100

typedef __attribute__((ext_vector_type(8))) short bf16x8;
typedef __attribute__((ext_vector_type(4))) float f32x4;

__device__ __forceinline__ unsigned short f2bf(float x) {
    unsigned u = __float_as_uint(x);
    unsigned r = (u + 0x7FFFu + ((u >> 16) & 1u)) >> 16;   // RNE
    return (unsigned short)r;
}

#define GLOAD_LDS16(g, s) __builtin_amdgcn_global_load_lds( \
    (const __attribute__((address_space(1))) void*)(g),     \
    (__attribute__((address_space(3))) void*)(s), 16, 0, 0)

// ---------------------------------------------------------------------------
// k0: convert Wih_f/Wih_b fp32 -> bf16 into padded layout Wpad[320][224]
// ---------------------------------------------------------------------------
__global__ __launch_bounds__(256) void k0_wpad(
    const float* __restrict__ Wih_f, const float* __restrict__ Wih_b,
    unsigned short* __restrict__ Wpad)
{
    int idx = blockIdx.x * 256 + threadIdx.x;
    if (idx >= 320 * 224) return;
    int row = idx / 224;
    int k   = idx - row * 224;
    int d   = row / 160;
    int r   = row - d * 160;
    float v = 0.f;
    if (r < G3 && k < EMB) v = (d ? Wih_b : Wih_f)[r * EMB + k];
    Wpad[idx] = f2bf(v);
}

// ---------------------------------------------------------------------------
// k1: gx = emb[tok] @ [Wih_f;Wih_b].T + bias, via bf16 MFMA 16x16x32.
// ---------------------------------------------------------------------------
__global__ __launch_bounds__(256) void k1_gx(
    const int* __restrict__ tokens, const float* __restrict__ emb,
    const unsigned short* __restrict__ Wpad,
    const float* __restrict__ bih_f, const float* __restrict__ bih_b,
    float* __restrict__ gx)
{
    __shared__ unsigned short Abuf[64 * 32];    // 4 KB
    __shared__ unsigned short Bbuf[320 * 32];   // 20 KB
    __shared__ float bias[320];
    __shared__ int tok[64];

    const int t = threadIdx.x;
    const int w = t >> 6;
    const int l = t & 63;
    const long row0 = (long)blockIdx.x * 64;

    for (int idx = t; idx < 320; idx += 256) {
        int d = idx / 160, r = idx - d * 160;
        bias[idx] = (r < G3) ? (d ? bih_b[r] : bih_f[r]) : 0.f;
    }
    if (t < 64) tok[t] = tokens[row0 + t];

    f32x4 acc[20];
    #pragma unroll
    for (int nt = 0; nt < 20; nt++) acc[nt] = (f32x4){0.f, 0.f, 0.f, 0.f};

    const int ar = t >> 2;
    const int kq = t & 3;
    __syncthreads();

    for (int c = 0; c < 7; c++) {
        const int kc0 = c * 32;
        float4 v0 = {0,0,0,0}, v1 = {0,0,0,0};
        if (kc0 + kq * 8 < EMB) {
            const float* src = emb + (long)tok[ar] * EMB + kc0 + kq * 8;
            v0 = *reinterpret_cast<const float4*>(src);
            v1 = *reinterpret_cast<const float4*>(src + 4);
        }
        __syncthreads();
        unsigned p0 = f2bf(v0.x) | ((unsigned)f2bf(v0.y) << 16);
        unsigned p1 = f2bf(v0.z) | ((unsigned)f2bf(v0.w) << 16);
        unsigned p2 = f2bf(v1.x) | ((unsigned)f2bf(v1.y) << 16);
        unsigned p3 = f2bf(v1.z) | ((unsigned)f2bf(v1.w) << 16);
        *reinterpret_cast<uint2*>(&Abuf[ar * 32 + kq * 8])     = make_uint2(p0, p1);
        *reinterpret_cast<uint2*>(&Abuf[ar * 32 + kq * 8 + 4]) = make_uint2(p2, p3);
        #pragma unroll
        for (int q = 0; q < 5; q++) {
            const int rbase = w * 80 + q * 16;
            const int rb = rbase + (l >> 2);
            const unsigned short* gsrc = Wpad + (long)rb * 224 + kc0 + (l & 3) * 8;
            GLOAD_LDS16(gsrc, &Bbuf[rbase * 32]);
        }
        __syncthreads();
        bf16x8 af = *reinterpret_cast<bf16x8*>(&Abuf[(w * 16 + (l & 15)) * 32 + (l >> 4) * 8]);
        #pragma unroll
        for (int nt = 0; nt < 20; nt++) {
            bf16x8 bfr = *reinterpret_cast<bf16x8*>(&Bbuf[(nt * 16 + (l & 15)) * 32 + (l >> 4) * 8]);
            acc[nt] = __builtin_amdgcn_mfma_f32_16x16x32_bf16(af, bfr, acc[nt], 0, 0, 0);
        }
    }

    const int colL  = l & 15;
    const int rquad = l >> 4;
    #pragma unroll
    for (int nt = 0; nt < 20; nt++) {
        int pcol = nt * 16 + colL;
        int d = pcol / 160;
        int jc = pcol - d * 160;
        if (jc >= G3) continue;
        float bv = bias[pcol];
        long col = d * G3 + jc;
        #pragma unroll
        for (int i = 0; i < 4; i++) {
            long row = row0 + w * 16 + rquad * 4 + i;
            gx[row * 300 + col] = acc[nt][i] + bv;
        }
    }
}

// ---------------------------------------------------------------------------
// k2: GRU scan — ONE WAVE per (batch, direction). Zero barriers in the loop.
// Lane l<50 owns rows {l, l+50, l+100} of Whh in registers (gates r,z,n for
// h-index l entirely in-lane). h broadcast via 13 ds_read_b128 (same-address
// broadcast, conflict-free). gx prefetched 2 steps ahead in registers.
// ---------------------------------------------------------------------------
#define K2_LOAD(S, VR, VZ, VN) do {                                        \
    int t_ = dir ? (SEQ - 1 - (S)) : (S);                                  \
    const float* p_ = gx + (long)t_ * (BATCH * 300) + base;                \
    VR = p_[0]; VZ = p_[50]; VN = p_[100];                                 \
} while (0)

#define K2_STEP(S, VR, VZ, VN) do {                                        \
    int t_ = dir ? (SEQ - 1 - (S)) : (S);                                  \
    float gxr_ = VR, gxz_ = VZ, gxn_ = VN;                                 \
    if ((S) + 2 < SEQ) K2_LOAD((S) + 2, VR, VZ, VN);                       \
    float4 h4_[13];                                                        \
    _Pragma("unroll")                                                      \
    for (int i_ = 0; i_ < 13; i_++)                                        \
        h4_[i_] = reinterpret_cast<float4*>(hs)[i_];                       \
    float ar_ = br, az_ = bz, an_ = bn;                                    \
    _Pragma("unroll")                                                      \
    for (int i_ = 0; i_ < 13; i_++) {                                      \
        ar_ = fmaf(wr[4*i_],   h4_[i_].x, ar_);                            \
        az_ = fmaf(wz[4*i_],   h4_[i_].x, az_);                            \
        an_ = fmaf(wn[4*i_],   h4_[i_].x, an_);                            \
        ar_ = fmaf(wr[4*i_+1], h4_[i_].y, ar_);                            \
        az_ = fmaf(wz[4*i_+1], h4_[i_].y, az_);                            \
        an_ = fmaf(wn[4*i_+1], h4_[i_].y, an_);                            \
        ar_ = fmaf(wr[4*i_+2], h4_[i_].z, ar_);                            \
        az_ = fmaf(wz[4*i_+2], h4_[i_].z, az_);                            \
        an_ = fmaf(wn[4*i_+2], h4_[i_].z, an_);                            \
        ar_ = fmaf(wr[4*i_+3], h4_[i_].w, ar_);                            \
        az_ = fmaf(wz[4*i_+3], h4_[i_].w, az_);                            \
        an_ = fmaf(wn[4*i_+3], h4_[i_].w, an_);                            \
    }                                                                      \
    float r_ = 1.f / (1.f + __expf(-(gxr_ + ar_)));                        \
    float z_ = 1.f / (1.f + __expf(-(gxz_ + az_)));                        \
    float x_ = gxn_ + r_ * an_;                                            \
    float e2_ = __expf(-2.f * x_);                                         \
    float n_ = (1.f - e2_) / (1.f + e2_);                                  \
    float hn_ = (1.f - z_) * n_ + z_ * hold;                               \
    hold = hn_;                                                            \
    h[((long)t_ * BATCH + b) * 100 + dir * 50 + l] = hn_;                  \
    hs[l] = hn_;                                                           \
} while (0)

__global__ __launch_bounds__(64) void k2_gru(
    const float* __restrict__ gx,
    const float* __restrict__ Whh_f, const float* __restrict__ bhh_f,
    const float* __restrict__ Whh_b, const float* __restrict__ bhh_b,
    float* __restrict__ h)
{
    const int b   = blockIdx.x & 255;
    const int dir = blockIdx.x >> 8;
    const float* __restrict__ Whh = dir ? Whh_b : Whh_f;
    const float* __restrict__ bhh = dir ? bhh_b : bhh_f;
    const int l = threadIdx.x;

    __shared__ alignas(16) float hs[52];

    // weights padded to 52 with zeros so the FMA loop is uniform
    float wr[52], wz[52], wn[52];
    float br = 0.f, bz = 0.f, bn = 0.f;

    if (l < 2) { hs[50 + l] = 0.f; }      // pad slots, never rewritten

    if (l < 50) {
        hs[l] = 0.f;
        br = bhh[l]; bz = bhh[l + 50]; bn = bhh[l + 100];
        #pragma unroll
        for (int k = 0; k < 50; k++) {
            wr[k] = Whh[l * HID + k];
            wz[k] = Whh[(l + 50) * HID + k];
            wn[k] = Whh[(l + 100) * HID + k];
        }
        wr[50] = wr[51] = wz[50] = wz[51] = wn[50] = wn[51] = 0.f;

        const long base = (long)b * 300 + dir * G3 + l;
        float hold = 0.f;
        float p0r, p0z, p0n, p1r, p1z, p1n;
        K2_LOAD(0, p0r, p0z, p0n);
        K2_LOAD(1, p1r, p1z, p1n);

        for (int s = 0; s < SEQ; s += 2) {
            K2_STEP(s,     p0r, p0z, p0n);
            K2_STEP(s + 1, p1r, p1z, p1n);
        }
    }
}

// ---------------------------------------------------------------------------
// k3: scores via thread-per-row; W_mlp in LDS, h row in registers.
// ---------------------------------------------------------------------------
__global__ __launch_bounds__(256) void k3_scores(
    const float* __restrict__ h, const float* __restrict__ W_mlp,
    const float* __restrict__ b_mlp, const float* __restrict__ ctx,
    float* __restrict__ scT)
{
    __shared__ float4 Wm[MLPN * 25];
    __shared__ float bm[MLPN], cx[MLPN];
    const int tid = threadIdx.x;
    for (int idx = tid; idx < MLPN * 25; idx += 256)
        Wm[idx] = reinterpret_cast<const float4*>(W_mlp)[idx];
    if (tid < MLPN) { bm[tid] = b_mlp[tid]; cx[tid] = ctx[tid]; }
    __syncthreads();

    const long row = (long)blockIdx.x * 256 + tid;
    float4 hr[25];
    const float4* hp = reinterpret_cast<const float4*>(h + row * 100);
    #pragma unroll
    for (int i = 0; i < 25; i++) hr[i] = hp[i];

    float s = 0.f;
    for (int jj = 0; jj < MLPN; jj++) {
        float acc = bm[jj];
        #pragma unroll
        for (int i = 0; i < 25; i++) {
            float4 wv = Wm[jj * 25 + i];
            acc += wv.x * hr[i].x + wv.y * hr[i].y + wv.z * hr[i].z + wv.w * hr[i].w;
        }
        float e2 = __expf(-2.f * acc);
        float u = (1.f - e2) / (1.f + e2);
        s += u * cx[jj];
    }
    const int t = (int)(row >> 8);
    const int b = (int)(row & 255);
    scT[(long)b * SEQ + t] = s;
}

// ---------------------------------------------------------------------------
// k4: per-batch softmax over t, then doc[b][i] = sum_t alpha[t]*h[t][b][i]
// ---------------------------------------------------------------------------
__global__ __launch_bounds__(128) void k4_doc(
    const float* __restrict__ h, const float* __restrict__ scT,
    float* __restrict__ out)
{
    const int b = blockIdx.x;
    const int tid = threadIdx.x;
    __shared__ float al[SEQ];
    __shared__ float red[128];

    float4 sv = reinterpret_cast<const float4*>(scT + (long)b * SEQ)[tid];
    float m = fmaxf(fmaxf(sv.x, sv.y), fmaxf(sv.z, sv.w));
    red[tid] = m;
    __syncthreads();
    if (tid < 64) red[tid] = fmaxf(red[tid], red[tid + 64]);
    __syncthreads();
    if (tid < 64) {
        float v = red[tid];
        for (int o = 32; o > 0; o >>= 1) v = fmaxf(v, __shfl_down(v, o));
        if (tid == 0) red[0] = v;
    }
    __syncthreads();
    m = red[0];
    float e0 = __expf(sv.x - m), e1 = __expf(sv.y - m);
    float e2 = __expf(sv.z - m), e3 = __expf(sv.w - m);
    float psum = e0 + e1 + e2 + e3;
    __syncthreads();
    red[tid] = psum;
    __syncthreads();
    if (tid < 64) red[tid] += red[tid + 64];
    __syncthreads();
    if (tid < 64) {
        float v = red[tid];
        for (int o = 32; o > 0; o >>= 1) v += __shfl_down(v, o);
        if (tid == 0) red[0] = v;
    }
    __syncthreads();
    const float inv = 1.f / red[0];
    al[tid * 4 + 0] = e0 * inv;
    al[tid * 4 + 1] = e1 * inv;
    al[tid * 4 + 2] = e2 * inv;
    al[tid * 4 + 3] = e3 * inv;
    __syncthreads();

    if (tid < MLPN) {
        float acc = 0.f;
        for (int t = 0; t < SEQ; t++)
            acc += al[t] * h[((long)t * BATCH + b) * 100 + tid];
        out[(long)b * 100 + tid] = acc;
    }
}

// ---------------------------------------------------------------------------
extern "C" void kernel_launch(void* const* d_in, const int* in_sizes, int n_in,
                              void* d_out, int out_size, void* d_ws, size_t ws_size,
                              hipStream_t stream)
{
    const int*   tokens = (const int*)d_in[0];
    const float* emb    = (const float*)d_in[1];
    const float* Wih_f  = (const float*)d_in[2];
    const float* Whh_f  = (const float*)d_in[3];
    const float* bih_f  = (const float*)d_in[4];
    const float* bhh_f  = (const float*)d_in[5];
    const float* Wih_b  = (const float*)d_in[6];
    const float* Whh_b  = (const float*)d_in[7];
    const float* bih_b  = (const float*)d_in[8];
    const float* bhh_b  = (const float*)d_in[9];
    const float* W_mlp  = (const float*)d_in[10];
    const float* b_mlp  = (const float*)d_in[11];
    const float* ctx    = (const float*)d_in[12];
    float* out = (float*)d_out;

    float* gx  = (float*)d_ws;                         // SEQ*BATCH*300
    float* h   = gx + (size_t)SEQ * BATCH * 300;       // SEQ*BATCH*100
    float* scT = h  + (size_t)SEQ * BATCH * 100;       // BATCH*SEQ
    unsigned short* Wpad = (unsigned short*)scT;       // aliased, dead before k3

    k0_wpad<<<280, 256, 0, stream>>>(Wih_f, Wih_b, Wpad);
    k1_gx<<<2048, 256, 0, stream>>>(tokens, emb, Wpad, bih_f, bih_b, gx);
    k2_gru<<<512, 64, 0, stream>>>(gx, Whh_f, bhh_f, Whh_b, bhh_b, h);
    k3_scores<<<512, 256, 0, stream>>>(h, W_mlp, b_mlp, ctx, scT);
    k4_doc<<<256, 128, 0, stream>>>(h, scT, out);
}